// Round 17
// baseline (353.089 us; speedup 1.0000x reference)
//
#include <hip/hip_runtime.h>
#include <math.h>

#define D 32
#define BN_EPS 1e-5f
#define NRANGE 512      // dst ranges; RW = ceil(N/NRANGE) = 196 @ N=100K
#define RWC 196         // compile-time RW bound (LDS sizing)
#define MAXD 80         // Poisson(32): P(deg>80) ~ 1e-11/node; 80 % 16 == 0
#define EPB 8192        // edges per block in build_part
#define K1_TPB 512
#define EPT (EPB / K1_TPB)   // 16 edges/thread, register-carried
#define PCH 8           // pool chunks per graph

// ============ K1: partition edges into per-range segments (register-carried) ============
__global__ __launch_bounds__(K1_TPB) void build_part(
    const int* __restrict__ src, const int* __restrict__ dst,
    unsigned int* __restrict__ part, int* __restrict__ gcount,
    int E, int cap, int RW, unsigned long long M) {
    __shared__ unsigned int sorted[EPB];      // 32 KB
    __shared__ unsigned short rid[EPB];       // 16 KB
    __shared__ int cnt[NRANGE];
    __shared__ int exc[NRANGE];
    __shared__ int cur[NRANGE];
    __shared__ int gbase[NRANGE];
    __shared__ int wsum[K1_TPB / 64];
    int t = threadIdx.x;
    cnt[t] = 0;                      // K1_TPB == NRANGE == 512
    __syncthreads();

    int base = blockIdx.x * EPB;
    int n = min(EPB, E - base);

    // pass A: load edges once into registers, count ranges
    unsigned int mypk[EPT];
    unsigned short myr[EPT];
#pragma unroll
    for (int k = 0; k < EPT; k++) {
        int i = t + k * K1_TPB;
        if (i < n) {
            int d = dst[base + i];
            int s = src[base + i];
            int r = (int)(((unsigned long long)d * M) >> 40);
            mypk[k] = ((unsigned)(d - r * RW) << 17) | (unsigned)s;
            myr[k] = (unsigned short)r;
            atomicAdd(&cnt[r], 1);
        } else myr[k] = 0xFFFFu;
    }
    __syncthreads();

    // wave-shfl scan over 512 bins (3 barriers instead of 18)
    int inc = cnt[t];
    int v = inc;
#pragma unroll
    for (int s = 1; s < 64; s <<= 1) {
        int u = __shfl_up(v, s, 64);
        if ((t & 63) >= s) v += u;
    }
    if ((t & 63) == 63) wsum[t >> 6] = v;
    __syncthreads();
    if (t == 0) {
        int acc = 0;
#pragma unroll
        for (int w = 0; w < K1_TPB / 64; w++) { int tmp = wsum[w]; wsum[w] = acc; acc += tmp; }
    }
    __syncthreads();
    int excl = v - inc + wsum[t >> 6];
    exc[t] = excl;
    cur[t] = excl;
    gbase[t] = atomicAdd(&gcount[t], cnt[t]);   // 1 global atomic per (block,range)
    __syncthreads();

    // pass B: scatter registers into LDS sorted-by-range
#pragma unroll
    for (int k = 0; k < EPT; k++) {
        if (myr[k] != 0xFFFFu) {
            int j = atomicAdd(&cur[myr[k]], 1);  // LDS
            sorted[j] = mypk[k];
            rid[j] = myr[k];
        }
    }
    __syncthreads();

    // write phase: linear stream out of LDS -> coalesced runs per range
    for (int j = t; j < n; j += K1_TPB) {
        int r = rid[j];
        int pos = gbase[r] + (j - exc[r]);
        if (pos < cap) part[(size_t)r * cap + pos] = sorted[j];
    }
}

// ============ y = x @ W1a (3->32), no bias ============
__global__ void compute_y(const float* __restrict__ x, const float* __restrict__ W1a,
                          float* __restrict__ y, int N) {
    long long gid = (long long)blockIdx.x * blockDim.x + threadIdx.x;
    int i = (int)(gid >> 5);
    int lane = (int)(gid & 31);
    if (i >= N) return;
    float x0 = x[i * 3 + 0], x1 = x[i * 3 + 1], x2 = x[i * 3 + 2];
    float t = x0 * W1a[0 * D + lane];
    t = fmaf(x1, W1a[1 * D + lane], t);
    t = fmaf(x2, W1a[2 * D + lane], t);
    y[(size_t)i * D + lane] = t;
}

// ============ K2: bucket-fill + col/deg writeout + FUSED layer 1 ============
// Phase 1 = old build_csr (rank pass, self-pad x16, coalesced col/deg writeout).
// Phase 2 = layer 1 for this range's nodes: indices via conflict-free LDS int4
// broadcasts (zero col-read requests), gathers from y, t=relu(acc+ba), Wb, BN.
__global__ __launch_bounds__(1024) void layer1_csr(
    const unsigned int* __restrict__ part, const int* __restrict__ gcount,
    int* __restrict__ col, int* __restrict__ deg,
    const float* __restrict__ y,
    const float* __restrict__ ba, const float* __restrict__ Wb,
    const float* __restrict__ bb, const float* __restrict__ g,
    const float* __restrict__ be, const float* __restrict__ m,
    const float* __restrict__ v, float* __restrict__ hout,
    int cap, int RW, int N, int maxd) {
    __shared__ int bucket[RWC * MAXD];   // 62.7 KB
    __shared__ int rank_[RWC];
    int r = blockIdx.x, t = threadIdx.x, T = blockDim.x;
    for (int i = t; i < RW; i += T) rank_[i] = 0;
    __syncthreads();

    int count = gcount[r]; if (count > cap) count = cap;
    const unsigned int* p = part + (size_t)r * cap;
    int nbase = r * RW;
    for (int i = t; i < count; i += T) {
        unsigned int pk = p[i];                // coalesced stream
        int dl = (int)(pk >> 17);
        int slot = atomicAdd(&rank_[dl], 1);   // LDS
        if (slot < maxd) bucket[dl * maxd + slot] = (int)(pk & 0x1FFFFu);
    }
    __syncthreads();

    // self-pad each row up to the next multiple of 16 (cancelled below / in layers)
    for (int i = t; i < RW; i += T) {
        int rk = rank_[i]; if (rk > maxd) rk = maxd;
        int pdg = (rk + 15) & ~15; if (pdg > maxd) pdg = maxd;
        int self = nbase + i;
        for (int k = rk; k < pdg; k++) bucket[i * maxd + k] = self;
    }
    __syncthreads();

    int nvalid = N - nbase; if (nvalid > RW) nvalid = RW;
    if (nvalid <= 0) return;
    // col/deg writeout first: stores drain underneath phase-2 gathers
    int words = nvalid * maxd;
    int4* dst4 = (int4*)&col[(size_t)nbase * maxd];
    const int4* src4 = (const int4*)bucket;
    int nq = words >> 2;
    for (int i = t; i < nq; i += T) dst4[i] = src4[i];
    for (int i = t; i < nvalid; i += T) {
        int rk = rank_[i];
        deg[nbase + i] = rk < maxd ? rk : maxd;
    }

    // phase 2: layer 1 (y-space: t = relu(agg_y + ba))
    int gidx = t >> 5, lane = t & 31;
    for (int nl = gidx; nl < nvalid; nl += 32) {
        int node = nbase + nl;
        int dg = rank_[nl]; if (dg > maxd) dg = maxd;
        int pdg = (dg + 15) & ~15; if (pdg > maxd) pdg = maxd;
        float acc = y[(size_t)node * D + lane] * (float)(1 + dg - pdg);
        const int* cp = &bucket[nl * maxd];     // LDS, 16B-aligned rows (maxd%16==0)
        int e = 0;
        for (; e + 32 <= pdg; e += 32) {
            int4 c0 = *(const int4*)&cp[e];
            int4 c1 = *(const int4*)&cp[e + 4];
            int4 c2 = *(const int4*)&cp[e + 8];
            int4 c3 = *(const int4*)&cp[e + 12];
            int4 c4 = *(const int4*)&cp[e + 16];
            int4 c5 = *(const int4*)&cp[e + 20];
            int4 c6 = *(const int4*)&cp[e + 24];
            int4 c7 = *(const int4*)&cp[e + 28];
            float a0 = y[(size_t)c0.x * D + lane];
            float a1 = y[(size_t)c0.y * D + lane];
            float a2 = y[(size_t)c0.z * D + lane];
            float a3 = y[(size_t)c0.w * D + lane];
            float a4 = y[(size_t)c1.x * D + lane];
            float a5 = y[(size_t)c1.y * D + lane];
            float a6 = y[(size_t)c1.z * D + lane];
            float a7 = y[(size_t)c1.w * D + lane];
            float a8 = y[(size_t)c2.x * D + lane];
            float a9 = y[(size_t)c2.y * D + lane];
            float a10 = y[(size_t)c2.z * D + lane];
            float a11 = y[(size_t)c2.w * D + lane];
            float a12 = y[(size_t)c3.x * D + lane];
            float a13 = y[(size_t)c3.y * D + lane];
            float a14 = y[(size_t)c3.z * D + lane];
            float a15 = y[(size_t)c3.w * D + lane];
            float a16 = y[(size_t)c4.x * D + lane];
            float a17 = y[(size_t)c4.y * D + lane];
            float a18 = y[(size_t)c4.z * D + lane];
            float a19 = y[(size_t)c4.w * D + lane];
            float a20 = y[(size_t)c5.x * D + lane];
            float a21 = y[(size_t)c5.y * D + lane];
            float a22 = y[(size_t)c5.z * D + lane];
            float a23 = y[(size_t)c5.w * D + lane];
            float a24 = y[(size_t)c6.x * D + lane];
            float a25 = y[(size_t)c6.y * D + lane];
            float a26 = y[(size_t)c6.z * D + lane];
            float a27 = y[(size_t)c6.w * D + lane];
            float a28 = y[(size_t)c7.x * D + lane];
            float a29 = y[(size_t)c7.y * D + lane];
            float a30 = y[(size_t)c7.z * D + lane];
            float a31 = y[(size_t)c7.w * D + lane];
            acc += (((a0 + a1) + (a2 + a3)) + ((a4 + a5) + (a6 + a7))) +
                   (((a8 + a9) + (a10 + a11)) + ((a12 + a13) + (a14 + a15))) +
                   (((a16 + a17) + (a18 + a19)) + ((a20 + a21) + (a22 + a23))) +
                   (((a24 + a25) + (a26 + a27)) + ((a28 + a29) + (a30 + a31)));
        }
        for (; e + 16 <= pdg; e += 16) {
            int4 c0 = *(const int4*)&cp[e];
            int4 c1 = *(const int4*)&cp[e + 4];
            int4 c2 = *(const int4*)&cp[e + 8];
            int4 c3 = *(const int4*)&cp[e + 12];
            float a0 = y[(size_t)c0.x * D + lane];
            float a1 = y[(size_t)c0.y * D + lane];
            float a2 = y[(size_t)c0.z * D + lane];
            float a3 = y[(size_t)c0.w * D + lane];
            float a4 = y[(size_t)c1.x * D + lane];
            float a5 = y[(size_t)c1.y * D + lane];
            float a6 = y[(size_t)c1.z * D + lane];
            float a7 = y[(size_t)c1.w * D + lane];
            float a8 = y[(size_t)c2.x * D + lane];
            float a9 = y[(size_t)c2.y * D + lane];
            float aa = y[(size_t)c2.z * D + lane];
            float ab = y[(size_t)c2.w * D + lane];
            float ac = y[(size_t)c3.x * D + lane];
            float ad = y[(size_t)c3.y * D + lane];
            float ae = y[(size_t)c3.z * D + lane];
            float af = y[(size_t)c3.w * D + lane];
            acc += ((a0 + a1) + (a2 + a3)) + ((a4 + a5) + (a6 + a7)) +
                   (((a8 + a9) + (aa + ab)) + ((ac + ad) + (ae + af)));
        }
        float tv = fmaxf(acc + ba[lane], 0.f);
        float o = bb[lane];
#pragma unroll
        for (int j = 0; j < D; j++) {
            float tj = __shfl(tv, j, D);
            o = fmaf(tj, Wb[j * D + lane], o);
        }
        o = fmaxf(o, 0.f);
        hout[(size_t)node * D + lane] =
            g[lane] * (o - m[lane]) * rsqrtf(v[lane] + BN_EPS) + be[lane];
    }
}

// ============ layers 2/3: R14-measured-best 32-wide direct-col gather ============
__global__ void layer_fused(const float* __restrict__ hin, const int* __restrict__ deg,
                            const int* __restrict__ col, int maxd,
                            const float* __restrict__ Wa, const float* __restrict__ ba,
                            const float* __restrict__ Wb, const float* __restrict__ bb,
                            const float* __restrict__ g, const float* __restrict__ be,
                            const float* __restrict__ m, const float* __restrict__ v,
                            float* __restrict__ hout, int N) {
    long long gid = (long long)blockIdx.x * blockDim.x + threadIdx.x;
    int i = (int)(gid >> 5);
    int lane = (int)(gid & 31);
    if (i >= N) return;

    int dg = deg[i];
    if (dg > maxd) dg = maxd;
    int pdg = (dg + 15) & ~15; if (pdg > maxd) pdg = maxd;
    float acc = hin[(size_t)i * D + lane] * (float)(1 + dg - pdg);
    const int* cp = &col[(size_t)i * maxd];
    int e = 0;
    for (; e + 32 <= pdg; e += 32) {
        int4 c0 = *(const int4*)&cp[e];
        int4 c1 = *(const int4*)&cp[e + 4];
        int4 c2 = *(const int4*)&cp[e + 8];
        int4 c3 = *(const int4*)&cp[e + 12];
        int4 c4 = *(const int4*)&cp[e + 16];
        int4 c5 = *(const int4*)&cp[e + 20];
        int4 c6 = *(const int4*)&cp[e + 24];
        int4 c7 = *(const int4*)&cp[e + 28];
        float a0 = hin[(size_t)c0.x * D + lane];
        float a1 = hin[(size_t)c0.y * D + lane];
        float a2 = hin[(size_t)c0.z * D + lane];
        float a3 = hin[(size_t)c0.w * D + lane];
        float a4 = hin[(size_t)c1.x * D + lane];
        float a5 = hin[(size_t)c1.y * D + lane];
        float a6 = hin[(size_t)c1.z * D + lane];
        float a7 = hin[(size_t)c1.w * D + lane];
        float a8 = hin[(size_t)c2.x * D + lane];
        float a9 = hin[(size_t)c2.y * D + lane];
        float a10 = hin[(size_t)c2.z * D + lane];
        float a11 = hin[(size_t)c2.w * D + lane];
        float a12 = hin[(size_t)c3.x * D + lane];
        float a13 = hin[(size_t)c3.y * D + lane];
        float a14 = hin[(size_t)c3.z * D + lane];
        float a15 = hin[(size_t)c3.w * D + lane];
        float a16 = hin[(size_t)c4.x * D + lane];
        float a17 = hin[(size_t)c4.y * D + lane];
        float a18 = hin[(size_t)c4.z * D + lane];
        float a19 = hin[(size_t)c4.w * D + lane];
        float a20 = hin[(size_t)c5.x * D + lane];
        float a21 = hin[(size_t)c5.y * D + lane];
        float a22 = hin[(size_t)c5.z * D + lane];
        float a23 = hin[(size_t)c5.w * D + lane];
        float a24 = hin[(size_t)c6.x * D + lane];
        float a25 = hin[(size_t)c6.y * D + lane];
        float a26 = hin[(size_t)c6.z * D + lane];
        float a27 = hin[(size_t)c6.w * D + lane];
        float a28 = hin[(size_t)c7.x * D + lane];
        float a29 = hin[(size_t)c7.y * D + lane];
        float a30 = hin[(size_t)c7.z * D + lane];
        float a31 = hin[(size_t)c7.w * D + lane];
        acc += (((a0 + a1) + (a2 + a3)) + ((a4 + a5) + (a6 + a7))) +
               (((a8 + a9) + (a10 + a11)) + ((a12 + a13) + (a14 + a15))) +
               (((a16 + a17) + (a18 + a19)) + ((a20 + a21) + (a22 + a23))) +
               (((a24 + a25) + (a26 + a27)) + ((a28 + a29) + (a30 + a31)));
    }
    for (; e + 16 <= pdg; e += 16) {
        int4 c0 = *(const int4*)&cp[e];
        int4 c1 = *(const int4*)&cp[e + 4];
        int4 c2 = *(const int4*)&cp[e + 8];
        int4 c3 = *(const int4*)&cp[e + 12];
        float a0 = hin[(size_t)c0.x * D + lane];
        float a1 = hin[(size_t)c0.y * D + lane];
        float a2 = hin[(size_t)c0.z * D + lane];
        float a3 = hin[(size_t)c0.w * D + lane];
        float a4 = hin[(size_t)c1.x * D + lane];
        float a5 = hin[(size_t)c1.y * D + lane];
        float a6 = hin[(size_t)c1.z * D + lane];
        float a7 = hin[(size_t)c1.w * D + lane];
        float a8 = hin[(size_t)c2.x * D + lane];
        float a9 = hin[(size_t)c2.y * D + lane];
        float aa = hin[(size_t)c2.z * D + lane];
        float ab = hin[(size_t)c2.w * D + lane];
        float ac = hin[(size_t)c3.x * D + lane];
        float ad = hin[(size_t)c3.y * D + lane];
        float ae = hin[(size_t)c3.z * D + lane];
        float af = hin[(size_t)c3.w * D + lane];
        acc += ((a0 + a1) + (a2 + a3)) + ((a4 + a5) + (a6 + a7)) +
               (((a8 + a9) + (aa + ab)) + ((ac + ad) + (ae + af)));
    }

    float t = ba[lane];
#pragma unroll
    for (int k = 0; k < D; k++) {
        float ak = __shfl(acc, k, D);
        t = fmaf(ak, Wa[k * D + lane], t);
    }
    t = fmaxf(t, 0.f);
    float o = bb[lane];
#pragma unroll
    for (int j = 0; j < D; j++) {
        float tj = __shfl(t, j, D);
        o = fmaf(tj, Wb[j * D + lane], o);
    }
    o = fmaxf(o, 0.f);
    hout[(size_t)i * D + lane] =
        g[lane] * (o - m[lane]) * rsqrtf(v[lane] + BN_EPS) + be[lane];
}

__device__ __forceinline__ int lower_bound_i(const int* a, int n, int key) {
    int lo = 0, hi = n;
    while (lo < hi) {
        int mid = (lo + hi) >> 1;
        if (a[mid] < key) lo = mid + 1; else hi = mid;
    }
    return lo;
}

__global__ void pool_partial(const float* __restrict__ h, const int* __restrict__ batch,
                             float* __restrict__ pool, int N, int G) {
    long long gid = (long long)blockIdx.x * blockDim.x + threadIdx.x;
    int grp = (int)(gid >> 5);
    int lane = (int)(gid & 31);
    int gi = grp / PCH;
    int c = grp - gi * PCH;
    if (gi >= G) return;
    int lo = lower_bound_i(batch, N, gi);
    int hi = lower_bound_i(batch, N, gi + 1);
    int len = hi - lo;
    if (len <= 0) return;
    int chunk = (len + PCH - 1) / PCH;
    int s = lo + c * chunk;
    int e = s + chunk; if (e > hi) e = hi;
    if (s >= e) return;
    float p = 0.f;
    for (int n = s; n < e; n++) p += h[(size_t)n * D + lane];
    atomicAdd(&pool[(size_t)gi * D + lane], p);
}

__global__ void head_kernel(const float* __restrict__ pool, const float* __restrict__ Wf1,
                            const float* __restrict__ bf1, const float* __restrict__ Wf2,
                            const float* __restrict__ bf2, float* __restrict__ out, int G) {
    long long gid = (long long)blockIdx.x * blockDim.x + threadIdx.x;
    int gi = (int)(gid >> 5);
    int lane = (int)(gid & 31);
    if (gi >= G) return;
    float p = pool[(size_t)gi * D + lane];
    float q = bf1[lane];
#pragma unroll
    for (int j = 0; j < D; j++) {
        float pj = __shfl(p, j, D);
        q = fmaf(pj, Wf1[j * D + lane], q);
    }
    q = fmaxf(q, 0.f);
    float r = q * Wf2[lane];
#pragma unroll
    for (int off = 16; off; off >>= 1) r += __shfl_xor(r, off, D);
    if (lane == 0) out[gi] = tanhf(r + bf2[0]);
}

extern "C" void kernel_launch(void* const* d_in, const int* in_sizes, int n_in,
                              void* d_out, int out_size, void* d_ws, size_t ws_size,
                              hipStream_t stream) {
    const float* x = (const float*)d_in[0];
    const int* ei = (const int*)d_in[1];
    const int* batch = (const int*)d_in[2];
    const int E = in_sizes[1] / 2;
    const int N = in_sizes[2];
    const int G = out_size;
    const int* src = ei;
    const int* dst = ei + E;

    const float* P[3][8];
    for (int l = 0; l < 3; l++)
        for (int k = 0; k < 8; k++) P[l][k] = (const float*)d_in[3 + 8 * l + k];
    const float* Wf1 = (const float*)d_in[27];
    const float* bf1 = (const float*)d_in[28];
    const float* Wf2 = (const float*)d_in[29];
    const float* bf2 = (const float*)d_in[30];

    const int RW = (N + NRANGE - 1) / NRANGE;                    // 196 @ N=100K (<= RWC)
    const unsigned long long M = ((1ull << 40) + RW - 1) / RW;   // magic div by RW
    int mean = (E + NRANGE - 1) / NRANGE;
    int cap = mean + mean / 8 + 64;    // ~+10 sigma slack, Binomial(E, 1/512)
    cap = (cap + 7) & ~7;

    // workspace (4B units)
    float* ws = (float*)d_ws;
    size_t off = 0;
    float* h0 = ws + off; off += (size_t)N * D;     // y, then layer-2 output
    float* h1 = ws + off; off += (size_t)N * D;
    unsigned int* part = (unsigned int*)(ws + off); off += (size_t)NRANGE * cap;
    int* deg = (int*)(ws + off); off += N;
    int* gcount = (int*)(ws + off); off += NRANGE;
    float* pool = ws + off; off += (size_t)G * D;   // adjacent to gcount: one memset
    int* col = (int*)(ws + off);
    size_t remaining = ws_size / 4 > off ? ws_size / 4 - off : 0;
    int maxd = (int)(remaining / (size_t)N);
    if (maxd > MAXD) maxd = MAXD;
    maxd &= ~15;                       // multiple of 16 (pad invariant)
    if (maxd < 16) maxd = 16;

    const int B = 256;
    long long tN32 = (long long)N * D;
    int nbp = (E + EPB - 1) / EPB;

    // ---- build + fused layer 1 ----
    hipMemsetAsync(gcount, 0, (NRANGE + (size_t)G * D) * sizeof(int), stream);
    compute_y<<<(int)((tN32 + B - 1) / B), B, 0, stream>>>(x, P[0][0], h0, N);
    build_part<<<nbp, K1_TPB, 0, stream>>>(src, dst, part, gcount, E, cap, RW, M);
    layer1_csr<<<NRANGE, 1024, 0, stream>>>(
        part, gcount, col, deg, h0, P[0][1], P[0][2], P[0][3],
        P[0][4], P[0][5], P[0][6], P[0][7], h1, cap, RW, N, maxd);

    // ---- layer 2: h1 -> h0 ----
    layer_fused<<<(int)((tN32 + B - 1) / B), B, 0, stream>>>(
        h1, deg, col, maxd, P[1][0], P[1][1], P[1][2], P[1][3],
        P[1][4], P[1][5], P[1][6], P[1][7], h0, N);

    // ---- layer 3: h0 -> h1 ----
    layer_fused<<<(int)((tN32 + B - 1) / B), B, 0, stream>>>(
        h0, deg, col, maxd, P[2][0], P[2][1], P[2][2], P[2][3],
        P[2][4], P[2][5], P[2][6], P[2][7], h1, N);

    // ---- chunked pool + head ----
    pool_partial<<<(int)(((long long)G * PCH * 32 + B - 1) / B), B, 0, stream>>>(
        h1, batch, pool, N, G);
    head_kernel<<<(int)(((long long)G * D + B - 1) / B), B, 0, stream>>>(
        pool, Wf1, bf1, Wf2, bf2, (float*)d_out, G);
}

// Round 18
// 352.608 us; speedup vs baseline: 1.0014x; 1.0014x over previous
//
#include <hip/hip_runtime.h>
#include <math.h>

#define D 32
#define BN_EPS 1e-5f
#define NRANGE 512      // dst ranges; RW = ceil(N/NRANGE) = 196 @ N=100K
#define RWC 196         // compile-time RW bound (LDS sizing)
#define MAXD 80         // Poisson(32): P(deg>80) ~ 1e-11/node; 80 % 16 == 0
#define EPB 4096        // edges per block in build_part (782 blocks = 3 occupancy rounds)
#define K1_TPB 512
#define EPT (EPB / K1_TPB)   // 8 edges/thread, register-carried
#define PCH 8           // pool chunks per graph

// ============ K1: partition edges into per-range segments (register-carried) ============
__global__ __launch_bounds__(K1_TPB) void build_part(
    const int* __restrict__ src, const int* __restrict__ dst,
    unsigned int* __restrict__ part, int* __restrict__ gcount,
    int E, int cap, int RW, unsigned long long M) {
    __shared__ unsigned int sorted[EPB];      // 16 KB
    __shared__ unsigned short rid[EPB];       // 8 KB
    __shared__ int cnt[NRANGE];
    __shared__ int exc[NRANGE];
    __shared__ int cur[NRANGE];
    __shared__ int gbase[NRANGE];
    __shared__ int wsum[K1_TPB / 64];
    int t = threadIdx.x;
    cnt[t] = 0;                      // K1_TPB == NRANGE == 512
    __syncthreads();

    int base = blockIdx.x * EPB;
    int n = min(EPB, E - base);

    // pass A: load edges once into registers, count ranges
    unsigned int mypk[EPT];
    unsigned short myr[EPT];
#pragma unroll
    for (int k = 0; k < EPT; k++) {
        int i = t + k * K1_TPB;
        if (i < n) {
            int d = dst[base + i];
            int s = src[base + i];
            int r = (int)(((unsigned long long)d * M) >> 40);
            mypk[k] = ((unsigned)(d - r * RW) << 17) | (unsigned)s;
            myr[k] = (unsigned short)r;
            atomicAdd(&cnt[r], 1);
        } else myr[k] = 0xFFFFu;
    }
    __syncthreads();

    // wave-shfl scan over 512 bins (3 barriers)
    int inc = cnt[t];
    int v = inc;
#pragma unroll
    for (int s = 1; s < 64; s <<= 1) {
        int u = __shfl_up(v, s, 64);
        if ((t & 63) >= s) v += u;
    }
    if ((t & 63) == 63) wsum[t >> 6] = v;
    __syncthreads();
    if (t == 0) {
        int acc = 0;
#pragma unroll
        for (int w = 0; w < K1_TPB / 64; w++) { int tmp = wsum[w]; wsum[w] = acc; acc += tmp; }
    }
    __syncthreads();
    int excl = v - inc + wsum[t >> 6];
    exc[t] = excl;
    cur[t] = excl;
    gbase[t] = atomicAdd(&gcount[t], cnt[t]);   // 1 global atomic per (block,range)
    __syncthreads();

    // pass B: scatter registers into LDS sorted-by-range
#pragma unroll
    for (int k = 0; k < EPT; k++) {
        if (myr[k] != 0xFFFFu) {
            int j = atomicAdd(&cur[myr[k]], 1);  // LDS
            sorted[j] = mypk[k];
            rid[j] = myr[k];
        }
    }
    __syncthreads();

    // write phase: linear stream out of LDS -> coalesced runs per range
    for (int j = t; j < n; j += K1_TPB) {
        int r = rid[j];
        int pos = gbase[r] + (j - exc[r]);
        if (pos < cap) part[(size_t)r * cap + pos] = sorted[j];
    }
}

// ============ K2: bucket-fill in LDS, self-pad x16, coalesced writeout, + fused y ============
__global__ __launch_bounds__(1024) void build_csr(
    const unsigned int* __restrict__ part, const int* __restrict__ gcount,
    int* __restrict__ col, int* __restrict__ deg,
    const float* __restrict__ x, const float* __restrict__ W1a, float* __restrict__ y,
    int cap, int RW, int N, int maxd) {
    __shared__ int bucket[RWC * MAXD];   // 62.7 KB
    __shared__ int rank_[RWC];
    int r = blockIdx.x, t = threadIdx.x, T = blockDim.x;
    for (int i = t; i < RW; i += T) rank_[i] = 0;
    __syncthreads();

    int count = gcount[r]; if (count > cap) count = cap;
    const unsigned int* p = part + (size_t)r * cap;
    int nbase = r * RW;
    for (int i = t; i < count; i += T) {
        unsigned int v = p[i];                 // coalesced stream
        int dl = (int)(v >> 17);
        int slot = atomicAdd(&rank_[dl], 1);   // LDS
        if (slot < maxd) bucket[dl * maxd + slot] = (int)(v & 0x1FFFFu);
    }
    __syncthreads();

    // self-pad each row up to the next multiple of 16 (cancelled in the layer)
    for (int i = t; i < RW; i += T) {
        int rk = rank_[i]; if (rk > maxd) rk = maxd;
        int pdg = (rk + 15) & ~15; if (pdg > maxd) pdg = maxd;
        int self = nbase + i;
        for (int k = rk; k < pdg; k++) bucket[i * maxd + k] = self;
    }
    __syncthreads();

    int nvalid = N - nbase; if (nvalid > RW) nvalid = RW;
    if (nvalid <= 0) return;
    int words = nvalid * maxd;
    int4* dst4 = (int4*)&col[(size_t)nbase * maxd];
    const int4* src4 = (const int4*)bucket;
    int nq = words >> 2;
    for (int i = t; i < nq; i += T) dst4[i] = src4[i];
    for (int i = t; i < nvalid; i += T) {
        int rk = rank_[i];
        deg[nbase + i] = rk < maxd ? rk : maxd;
    }

    // fused compute_y for this range's nodes: y = x @ W1a (no bias)
    int gidx = t >> 5, lane = t & 31;
    for (int nl = gidx; nl < nvalid; nl += 32) {
        int node = nbase + nl;
        float x0 = x[node * 3 + 0], x1 = x[node * 3 + 1], x2 = x[node * 3 + 2];
        float tv = x0 * W1a[0 * D + lane];
        tv = fmaf(x1, W1a[1 * D + lane], tv);
        tv = fmaf(x2, W1a[2 * D + lane], tv);
        y[(size_t)node * D + lane] = tv;
    }
}

// ============ layers: measured-best 32-wide direct-col gather ============
template <bool SKIP_WA>
__global__ void layer_fused(const float* __restrict__ hin, const int* __restrict__ deg,
                            const int* __restrict__ col, int maxd,
                            const float* __restrict__ Wa, const float* __restrict__ ba,
                            const float* __restrict__ Wb, const float* __restrict__ bb,
                            const float* __restrict__ g, const float* __restrict__ be,
                            const float* __restrict__ m, const float* __restrict__ v,
                            float* __restrict__ hout, int N) {
    long long gid = (long long)blockIdx.x * blockDim.x + threadIdx.x;
    int i = (int)(gid >> 5);
    int lane = (int)(gid & 31);
    if (i >= N) return;

    int dg = deg[i];
    if (dg > maxd) dg = maxd;
    int pdg = (dg + 15) & ~15; if (pdg > maxd) pdg = maxd;
    float acc = hin[(size_t)i * D + lane] * (float)(1 + dg - pdg);
    const int* cp = &col[(size_t)i * maxd];
    int e = 0;
    for (; e + 32 <= pdg; e += 32) {         // 32 outstanding gathers: 1 latency round
        int4 c0 = *(const int4*)&cp[e];
        int4 c1 = *(const int4*)&cp[e + 4];
        int4 c2 = *(const int4*)&cp[e + 8];
        int4 c3 = *(const int4*)&cp[e + 12];
        int4 c4 = *(const int4*)&cp[e + 16];
        int4 c5 = *(const int4*)&cp[e + 20];
        int4 c6 = *(const int4*)&cp[e + 24];
        int4 c7 = *(const int4*)&cp[e + 28];
        float a0 = hin[(size_t)c0.x * D + lane];
        float a1 = hin[(size_t)c0.y * D + lane];
        float a2 = hin[(size_t)c0.z * D + lane];
        float a3 = hin[(size_t)c0.w * D + lane];
        float a4 = hin[(size_t)c1.x * D + lane];
        float a5 = hin[(size_t)c1.y * D + lane];
        float a6 = hin[(size_t)c1.z * D + lane];
        float a7 = hin[(size_t)c1.w * D + lane];
        float a8 = hin[(size_t)c2.x * D + lane];
        float a9 = hin[(size_t)c2.y * D + lane];
        float a10 = hin[(size_t)c2.z * D + lane];
        float a11 = hin[(size_t)c2.w * D + lane];
        float a12 = hin[(size_t)c3.x * D + lane];
        float a13 = hin[(size_t)c3.y * D + lane];
        float a14 = hin[(size_t)c3.z * D + lane];
        float a15 = hin[(size_t)c3.w * D + lane];
        float a16 = hin[(size_t)c4.x * D + lane];
        float a17 = hin[(size_t)c4.y * D + lane];
        float a18 = hin[(size_t)c4.z * D + lane];
        float a19 = hin[(size_t)c4.w * D + lane];
        float a20 = hin[(size_t)c5.x * D + lane];
        float a21 = hin[(size_t)c5.y * D + lane];
        float a22 = hin[(size_t)c5.z * D + lane];
        float a23 = hin[(size_t)c5.w * D + lane];
        float a24 = hin[(size_t)c6.x * D + lane];
        float a25 = hin[(size_t)c6.y * D + lane];
        float a26 = hin[(size_t)c6.z * D + lane];
        float a27 = hin[(size_t)c6.w * D + lane];
        float a28 = hin[(size_t)c7.x * D + lane];
        float a29 = hin[(size_t)c7.y * D + lane];
        float a30 = hin[(size_t)c7.z * D + lane];
        float a31 = hin[(size_t)c7.w * D + lane];
        acc += (((a0 + a1) + (a2 + a3)) + ((a4 + a5) + (a6 + a7))) +
               (((a8 + a9) + (a10 + a11)) + ((a12 + a13) + (a14 + a15))) +
               (((a16 + a17) + (a18 + a19)) + ((a20 + a21) + (a22 + a23))) +
               (((a24 + a25) + (a26 + a27)) + ((a28 + a29) + (a30 + a31)));
    }
    for (; e + 16 <= pdg; e += 16) {         // at most one (pdg % 16 == 0)
        int4 c0 = *(const int4*)&cp[e];
        int4 c1 = *(const int4*)&cp[e + 4];
        int4 c2 = *(const int4*)&cp[e + 8];
        int4 c3 = *(const int4*)&cp[e + 12];
        float a0 = hin[(size_t)c0.x * D + lane];
        float a1 = hin[(size_t)c0.y * D + lane];
        float a2 = hin[(size_t)c0.z * D + lane];
        float a3 = hin[(size_t)c0.w * D + lane];
        float a4 = hin[(size_t)c1.x * D + lane];
        float a5 = hin[(size_t)c1.y * D + lane];
        float a6 = hin[(size_t)c1.z * D + lane];
        float a7 = hin[(size_t)c1.w * D + lane];
        float a8 = hin[(size_t)c2.x * D + lane];
        float a9 = hin[(size_t)c2.y * D + lane];
        float aa = hin[(size_t)c2.z * D + lane];
        float ab = hin[(size_t)c2.w * D + lane];
        float ac = hin[(size_t)c3.x * D + lane];
        float ad = hin[(size_t)c3.y * D + lane];
        float ae = hin[(size_t)c3.z * D + lane];
        float af = hin[(size_t)c3.w * D + lane];
        acc += ((a0 + a1) + (a2 + a3)) + ((a4 + a5) + (a6 + a7)) +
               (((a8 + a9) + (aa + ab)) + ((ac + ad) + (ae + af)));
    }

    float t;
    if (SKIP_WA) {
        t = fmaxf(acc + ba[lane], 0.f);
    } else {
        t = ba[lane];
#pragma unroll
        for (int k = 0; k < D; k++) {
            float ak = __shfl(acc, k, D);
            t = fmaf(ak, Wa[k * D + lane], t);
        }
        t = fmaxf(t, 0.f);
    }
    float o = bb[lane];
#pragma unroll
    for (int j = 0; j < D; j++) {
        float tj = __shfl(t, j, D);
        o = fmaf(tj, Wb[j * D + lane], o);
    }
    o = fmaxf(o, 0.f);
    hout[(size_t)i * D + lane] =
        g[lane] * (o - m[lane]) * rsqrtf(v[lane] + BN_EPS) + be[lane];
}

__device__ __forceinline__ int lower_bound_i(const int* a, int n, int key) {
    int lo = 0, hi = n;
    while (lo < hi) {
        int mid = (lo + hi) >> 1;
        if (a[mid] < key) lo = mid + 1; else hi = mid;
    }
    return lo;
}

__global__ void pool_partial(const float* __restrict__ h, const int* __restrict__ batch,
                             float* __restrict__ pool, int N, int G) {
    long long gid = (long long)blockIdx.x * blockDim.x + threadIdx.x;
    int grp = (int)(gid >> 5);
    int lane = (int)(gid & 31);
    int gi = grp / PCH;
    int c = grp - gi * PCH;
    if (gi >= G) return;
    int lo = lower_bound_i(batch, N, gi);
    int hi = lower_bound_i(batch, N, gi + 1);
    int len = hi - lo;
    if (len <= 0) return;
    int chunk = (len + PCH - 1) / PCH;
    int s = lo + c * chunk;
    int e = s + chunk; if (e > hi) e = hi;
    if (s >= e) return;
    float p = 0.f;
    for (int n = s; n < e; n++) p += h[(size_t)n * D + lane];
    atomicAdd(&pool[(size_t)gi * D + lane], p);
}

__global__ void head_kernel(const float* __restrict__ pool, const float* __restrict__ Wf1,
                            const float* __restrict__ bf1, const float* __restrict__ Wf2,
                            const float* __restrict__ bf2, float* __restrict__ out, int G) {
    long long gid = (long long)blockIdx.x * blockDim.x + threadIdx.x;
    int gi = (int)(gid >> 5);
    int lane = (int)(gid & 31);
    if (gi >= G) return;
    float p = pool[(size_t)gi * D + lane];
    float q = bf1[lane];
#pragma unroll
    for (int j = 0; j < D; j++) {
        float pj = __shfl(p, j, D);
        q = fmaf(pj, Wf1[j * D + lane], q);
    }
    q = fmaxf(q, 0.f);
    float r = q * Wf2[lane];
#pragma unroll
    for (int off = 16; off; off >>= 1) r += __shfl_xor(r, off, D);
    if (lane == 0) out[gi] = tanhf(r + bf2[0]);
}

extern "C" void kernel_launch(void* const* d_in, const int* in_sizes, int n_in,
                              void* d_out, int out_size, void* d_ws, size_t ws_size,
                              hipStream_t stream) {
    const float* x = (const float*)d_in[0];
    const int* ei = (const int*)d_in[1];
    const int* batch = (const int*)d_in[2];
    const int E = in_sizes[1] / 2;
    const int N = in_sizes[2];
    const int G = out_size;
    const int* src = ei;
    const int* dst = ei + E;

    const float* P[3][8];
    for (int l = 0; l < 3; l++)
        for (int k = 0; k < 8; k++) P[l][k] = (const float*)d_in[3 + 8 * l + k];
    const float* Wf1 = (const float*)d_in[27];
    const float* bf1 = (const float*)d_in[28];
    const float* Wf2 = (const float*)d_in[29];
    const float* bf2 = (const float*)d_in[30];

    const int RW = (N + NRANGE - 1) / NRANGE;                    // 196 @ N=100K (<= RWC)
    const unsigned long long M = ((1ull << 40) + RW - 1) / RW;   // magic div by RW
    int mean = (E + NRANGE - 1) / NRANGE;
    int cap = mean + mean / 8 + 64;    // ~+10 sigma slack, Binomial(E, 1/512)
    cap = (cap + 7) & ~7;

    // workspace (4B units). part is its own region (y-write overlaps build_csr).
    float* ws = (float*)d_ws;
    size_t off = 0;
    float* h0 = ws + off; off += (size_t)N * D;
    float* h1 = ws + off; off += (size_t)N * D;
    unsigned int* part = (unsigned int*)(ws + off); off += (size_t)NRANGE * cap;
    int* deg = (int*)(ws + off); off += N;
    int* gcount = (int*)(ws + off); off += NRANGE;
    float* pool = ws + off; off += (size_t)G * D;   // adjacent to gcount: one memset
    int* col = (int*)(ws + off);
    size_t remaining = ws_size / 4 > off ? ws_size / 4 - off : 0;
    int maxd = (int)(remaining / (size_t)N);
    if (maxd > MAXD) maxd = MAXD;
    maxd &= ~15;                       // multiple of 16 (pad invariant)
    if (maxd < 16) maxd = 16;

    const int B = 256;
    long long tN32 = (long long)N * D;
    int nbp = (E + EPB - 1) / EPB;

    // ---- adjacency build + fused y ----
    hipMemsetAsync(gcount, 0, (NRANGE + (size_t)G * D) * sizeof(int), stream);
    build_part<<<nbp, K1_TPB, 0, stream>>>(src, dst, part, gcount, E, cap, RW, M);
    build_csr<<<NRANGE, 1024, 0, stream>>>(part, gcount, col, deg, x, P[0][0], h0,
                                           cap, RW, N, maxd);

    // ---- layer 1 (y-space: (x+agg_x)@W1a == y+agg_y, y=x@W1a) ----
    layer_fused<true><<<(int)((tN32 + B - 1) / B), B, 0, stream>>>(
        h0, deg, col, maxd, P[0][0], P[0][1], P[0][2], P[0][3],
        P[0][4], P[0][5], P[0][6], P[0][7], h1, N);

    // ---- layer 2: h1 -> h0 ----
    layer_fused<false><<<(int)((tN32 + B - 1) / B), B, 0, stream>>>(
        h1, deg, col, maxd, P[1][0], P[1][1], P[1][2], P[1][3],
        P[1][4], P[1][5], P[1][6], P[1][7], h0, N);

    // ---- layer 3: h0 -> h1 ----
    layer_fused<false><<<(int)((tN32 + B - 1) / B), B, 0, stream>>>(
        h0, deg, col, maxd, P[2][0], P[2][1], P[2][2], P[2][3],
        P[2][4], P[2][5], P[2][6], P[2][7], h1, N);

    // ---- chunked pool + head ----
    pool_partial<<<(int)(((long long)G * PCH * 32 + B - 1) / B), B, 0, stream>>>(
        h1, batch, pool, N, G);
    head_kernel<<<(int)(((long long)G * D + B - 1) / B), B, 0, stream>>>(
        pool, Wf1, bf1, Wf2, bf2, (float*)d_out, G);
}